// Round 1
// baseline (359.645 us; speedup 1.0000x reference)
//
#include <hip/hip_runtime.h>

// Shapes (fixed by setup_inputs): N=1, L1=256, K=128, L2=1024,
// c_s=384, c_m=256, ch=32, c_z=128
#define L1V 256
#define L2V 1024
#define KV  128
#define CSV 384
#define CMV 256
#define CHV 32
#define CZV 128

__device__ __forceinline__ float4 f4zero() { return make_float4(0.f,0.f,0.f,0.f); }

// ---------------------------------------------------------------------------
// Kernel A: m_sum[j,c] = sum_k (LN(m[k,j,:]) * g + b) @ W_ag + K*b_ag
// Key algebra: sum over k commutes inside the linear projection, so we
// accumulate xsum[e] = sum_k xhat_k[e] per j and project ONCE per j.
// grid = 1024 (one block per j), block = 256 (4 waves; wave w does k = w,w+4,...)
// ---------------------------------------------------------------------------
__global__ __launch_bounds__(256) void msum_kernel(
    const float* __restrict__ m, const float* __restrict__ g,
    const float* __restrict__ b, const float* __restrict__ Wag,
    const float* __restrict__ bag, float* __restrict__ msum)
{
  const int j    = blockIdx.x;
  const int tid  = threadIdx.x;
  const int wave = tid >> 6;
  const int lane = tid & 63;

  const float4* base = (const float4*)m;  // row k starts at float4 index (k*1024+j)*64

  float4 xs = f4zero();
  float4 x  = base[(((size_t)wave << 10) + j) * 64 + lane];

  for (int k = wave; k < KV; k += 4) {
    const int kn = k + 4;
    float4 xn = f4zero();
    if (kn < KV) xn = base[(((size_t)kn << 10) + j) * 64 + lane];  // prefetch next row

    float s1 = x.x + x.y + x.z + x.w;
    float s2 = x.x*x.x + x.y*x.y + x.z*x.z + x.w*x.w;
    #pragma unroll
    for (int off = 32; off > 0; off >>= 1) {
      s1 += __shfl_xor(s1, off, 64);
      s2 += __shfl_xor(s2, off, 64);
    }
    const float mu   = s1 * (1.0f / CMV);
    const float rstd = rsqrtf(s2 * (1.0f / CMV) - mu * mu + 1e-5f);
    xs.x = fmaf(x.x - mu, rstd, xs.x);
    xs.y = fmaf(x.y - mu, rstd, xs.y);
    xs.z = fmaf(x.z - mu, rstd, xs.z);
    xs.w = fmaf(x.w - mu, rstd, xs.w);
    x = xn;
  }

  __shared__ float xsum[4][CMV];
  ((float4*)xsum[wave])[lane] = xs;
  __syncthreads();

  // y[e] = xsum_total[e]*g[e] + K*b[e]  (folds LN affine + K-sum of bias)
  __shared__ float y[CMV];
  y[tid] = (xsum[0][tid] + xsum[1][tid] + xsum[2][tid] + xsum[3][tid]) * g[tid]
           + (float)KV * b[tid];
  __syncthreads();

  // projection: thread t handles c = t&31, e-chunk = t>>5 (8 chunks of 32)
  const int c     = tid & 31;
  const int chunk = tid >> 5;
  float p = 0.f;
  #pragma unroll
  for (int q = 0; q < 32; ++q) {
    const int e = (chunk << 5) + q;
    p = fmaf(y[e], Wag[(e << 5) + c], p);
  }
  __shared__ float pr[256];
  pr[tid] = p;
  __syncthreads();
  if (tid < 32) {
    float acc = 0.f;
    #pragma unroll
    for (int r = 0; r < 8; ++r) acc += pr[tid + (r << 5)];
    msum[(j << 5) + tid] = acc + (float)KV * bag[tid];
  }
}

// ---------------------------------------------------------------------------
// Kernel B1: a[i,c] = (LN(s[i,:])*g + b) @ W_ab + b_ab
// grid = 256 (one block per row i), block = 384 (one thread per element)
// ---------------------------------------------------------------------------
__global__ __launch_bounds__(384) void a_kernel(
    const float* __restrict__ s, const float* __restrict__ g,
    const float* __restrict__ b, const float* __restrict__ Wab,
    const float* __restrict__ bab, float* __restrict__ a)
{
  const int i    = blockIdx.x;
  const int tid  = threadIdx.x;
  const int wave = tid >> 6;   // 0..5
  const int lane = tid & 63;

  const float x = s[i * CSV + tid];
  float s1 = x, s2 = x * x;
  #pragma unroll
  for (int off = 32; off > 0; off >>= 1) {
    s1 += __shfl_xor(s1, off, 64);
    s2 += __shfl_xor(s2, off, 64);
  }
  __shared__ float r1[6], r2[6];
  if (lane == 0) { r1[wave] = s1; r2[wave] = s2; }
  __syncthreads();
  float t1 = 0.f, t2 = 0.f;
  #pragma unroll
  for (int w = 0; w < 6; ++w) { t1 += r1[w]; t2 += r2[w]; }
  const float mu   = t1 * (1.0f / CSV);
  const float rstd = rsqrtf(t2 * (1.0f / CSV) - mu * mu + 1e-5f);

  __shared__ float y[CSV];
  y[tid] = (x - mu) * rstd * g[tid] + b[tid];
  __syncthreads();

  const int c     = tid & 31;
  const int chunk = tid >> 5;  // 0..11
  float p = 0.f;
  #pragma unroll
  for (int q = 0; q < 32; ++q) {
    const int e = (chunk << 5) + q;
    p = fmaf(y[e], Wab[(e << 5) + c], p);
  }
  __shared__ float pr[CSV];
  pr[tid] = p;
  __syncthreads();
  if (tid < 32) {
    float acc = 0.f;
    #pragma unroll
    for (int r = 0; r < 12; ++r) acc += pr[tid + (r << 5)];
    a[(i << 5) + tid] = acc + bab[tid];
  }
}

// ---------------------------------------------------------------------------
// Kernel B2: T[i,e,z] = sum_c a[i,c] * W_out[c*4096 + e*128 + z]
// grid = 256 (one block per i), block = 256; W_out (512 KB) stays hot in L2.
// ---------------------------------------------------------------------------
__global__ __launch_bounds__(256) void t_kernel(
    const float* __restrict__ a, const float* __restrict__ Wout,
    float* __restrict__ T)
{
  const int i   = blockIdx.x;
  const int tid = threadIdx.x;
  __shared__ float as[CHV];
  if (tid < CHV) as[tid] = a[(i << 5) + tid];
  __syncthreads();
  #pragma unroll 4
  for (int rep = 0; rep < 16; ++rep) {
    const int idx = (rep << 8) + tid;   // 0..4095 == e*128+z
    float acc = 0.f;
    #pragma unroll
    for (int c = 0; c < CHV; ++c)
      acc = fmaf(as[c], Wout[(c << 12) + idx], acc);
    T[((size_t)i << 12) + idx] = acc;
  }
}

// ---------------------------------------------------------------------------
// Kernel C: out[i,j,z] = (m_sum[j,:] @ T[i][:,z] + b_out[z]) / (K + 1e-3)
// grid = (16 j-tiles, 256 i), block = 256.
// Each thread owns a z-quad (4 consecutive z) -> T column quad in 128 VGPRs,
// loops 8 j's; m_sum tile (64x32 = 8 KB) staged in LDS, read as b128 broadcast.
// ---------------------------------------------------------------------------
__global__ __launch_bounds__(256) void out_kernel(
    const float* __restrict__ msum, const float* __restrict__ T,
    const float* __restrict__ bout, float* __restrict__ out)
{
  const int tile = blockIdx.x;   // 0..15
  const int i    = blockIdx.y;   // 0..255
  const int tid  = threadIdx.x;
  const int j0   = tile << 6;

  __shared__ float ms[64 * CHV];  // 2048 floats = 8 KB
  {
    const float4* src = (const float4*)(msum + ((size_t)j0 << 5));
    float4* dst = (float4*)ms;
    dst[tid]       = src[tid];
    dst[tid + 256] = src[tid + 256];
  }

  const int zq = (tid & 31) << 2;  // z quad start: 0,4,...,124
  const int jg = tid >> 5;         // 0..7

  float4 Treg[32];
  #pragma unroll
  for (int e = 0; e < 32; ++e)
    Treg[e] = *(const float4*)(T + ((size_t)i << 12) + (e << 7) + zq);

  __syncthreads();

  const float4 bz = *(const float4*)(bout + zq);
  const float inv_norm = 1.0f / ((float)KV + 1e-3f);

  #pragma unroll
  for (int jj = 0; jj < 8; ++jj) {
    const int j = jg + (jj << 3);            // 0..63
    const float4* mr = (const float4*)(ms + (j << 5));
    float4 acc = f4zero();
    #pragma unroll
    for (int eq = 0; eq < 8; ++eq) {
      const float4 m4 = mr[eq];
      const float4 t0 = Treg[(eq << 2) + 0];
      const float4 t1 = Treg[(eq << 2) + 1];
      const float4 t2 = Treg[(eq << 2) + 2];
      const float4 t3 = Treg[(eq << 2) + 3];
      acc.x = fmaf(m4.x, t0.x, fmaf(m4.y, t1.x, fmaf(m4.z, t2.x, fmaf(m4.w, t3.x, acc.x))));
      acc.y = fmaf(m4.x, t0.y, fmaf(m4.y, t1.y, fmaf(m4.z, t2.y, fmaf(m4.w, t3.y, acc.y))));
      acc.z = fmaf(m4.x, t0.z, fmaf(m4.y, t1.z, fmaf(m4.z, t2.z, fmaf(m4.w, t3.z, acc.z))));
      acc.w = fmaf(m4.x, t0.w, fmaf(m4.y, t1.w, fmaf(m4.z, t2.w, fmaf(m4.w, t3.w, acc.w))));
    }
    float4 o;
    o.x = (acc.x + bz.x) * inv_norm;
    o.y = (acc.y + bz.y) * inv_norm;
    o.z = (acc.z + bz.z) * inv_norm;
    o.w = (acc.w + bz.w) * inv_norm;
    *(float4*)(out + ((size_t)i << 17) + ((size_t)(j0 + j) << 7) + zq) = o;
  }
}

// ---------------------------------------------------------------------------
extern "C" void kernel_launch(void* const* d_in, const int* in_sizes, int n_in,
                              void* d_out, int out_size, void* d_ws, size_t ws_size,
                              hipStream_t stream) {
  (void)in_sizes; (void)n_in; (void)out_size; (void)ws_size;
  const float* s    = (const float*)d_in[0];
  const float* m    = (const float*)d_in[1];
  const float* g_ab = (const float*)d_in[2];
  const float* b_ab = (const float*)d_in[3];
  const float* g_ag = (const float*)d_in[4];
  const float* b_ag = (const float*)d_in[5];
  const float* Wab  = (const float*)d_in[6];
  const float* bab  = (const float*)d_in[7];
  const float* Wag  = (const float*)d_in[8];
  const float* bag  = (const float*)d_in[9];
  const float* Wout = (const float*)d_in[10];
  const float* bout = (const float*)d_in[11];
  float* out = (float*)d_out;

  // workspace layout (fp32): msum[1024*32] | a[256*32] | T[256*32*128]
  float* msum = (float*)d_ws;
  float* a    = msum + 32768;
  float* T    = a + 8192;   // 4 MB

  hipLaunchKernelGGL(msum_kernel, dim3(1024), dim3(256), 0, stream,
                     m, g_ag, b_ag, Wag, bag, msum);
  hipLaunchKernelGGL(a_kernel, dim3(256), dim3(384), 0, stream,
                     s, g_ab, b_ab, Wab, bab, a);
  hipLaunchKernelGGL(t_kernel, dim3(256), dim3(256), 0, stream,
                     a, Wout, T);
  hipLaunchKernelGGL(out_kernel, dim3(16, 256), dim3(256), 0, stream,
                     msum, T, bout, out);
}

// Round 2
// 299.485 us; speedup vs baseline: 1.2009x; 1.2009x over previous
//
#include <hip/hip_runtime.h>

// Shapes (fixed by setup_inputs): N=1, L1=256, K=128, L2=1024,
// c_s=384, c_m=256, ch=32, c_z=128
#define L1V 256
#define L2V 1024
#define KV  128
#define CSV 384
#define CMV 256
#define CHV 32
#define CZV 128

__device__ __forceinline__ float4 f4zero() { return make_float4(0.f,0.f,0.f,0.f); }

// Per-row LN stats (full-wave reduction over 256 elems = 64 lanes x float4),
// then accumulate normalized row into xs. Two calls back-to-back give the
// compiler two independent 6-deep shuffle chains to interleave.
__device__ __forceinline__ void ln_accum(const float4 x, float4& xs) {
  float s1 = x.x + x.y + x.z + x.w;
  float s2 = fmaf(x.x, x.x, fmaf(x.y, x.y, fmaf(x.z, x.z, x.w * x.w)));
  #pragma unroll
  for (int off = 32; off > 0; off >>= 1) {
    s1 += __shfl_xor(s1, off, 64);
    s2 += __shfl_xor(s2, off, 64);
  }
  const float mu   = s1 * (1.0f / CMV);
  const float rstd = rsqrtf(s2 * (1.0f / CMV) - mu * mu + 1e-5f);
  xs.x = fmaf(x.x - mu, rstd, xs.x);
  xs.y = fmaf(x.y - mu, rstd, xs.y);
  xs.z = fmaf(x.z - mu, rstd, xs.z);
  xs.w = fmaf(x.w - mu, rstd, xs.w);
}

// ---------------------------------------------------------------------------
// Kernel A: m_sum[j,c] = sum_k (LN(m[k,j,:]) * g + b) @ W_ag + K*b_ag
// K-sum commutes inside the projection -> accumulate xhat, project once per j.
// grid = 1024 (block per j), block = 256 (4 waves; wave w does k = w,w+4,...)
// Unroll-2 over k: 2 rows in flight doubles outstanding loads + shuffle ILP.
// ---------------------------------------------------------------------------
__global__ __launch_bounds__(256) void msum_kernel(
    const float* __restrict__ m, const float* __restrict__ g,
    const float* __restrict__ b, const float* __restrict__ Wag,
    const float* __restrict__ bag, float* __restrict__ msum)
{
  const int j    = blockIdx.x;
  const int tid  = threadIdx.x;
  const int wave = tid >> 6;
  const int lane = tid & 63;

  const float4* base = (const float4*)m;  // row k at float4 index (k*1024+j)*64

  float4 xs = f4zero();
  float4 x0 = base[(((size_t)wave << 10) + j) * 64 + lane];
  float4 x1 = base[(((size_t)(wave + 4) << 10) + j) * 64 + lane];

  for (int k = wave; k < KV; k += 8) {
    float4 n0 = f4zero(), n1 = f4zero();
    if (k + 8  < KV) n0 = base[(((size_t)(k + 8)  << 10) + j) * 64 + lane];
    if (k + 12 < KV) n1 = base[(((size_t)(k + 12) << 10) + j) * 64 + lane];
    ln_accum(x0, xs);
    ln_accum(x1, xs);
    x0 = n0; x1 = n1;
  }

  __shared__ float xsum[4][CMV];
  ((float4*)xsum[wave])[lane] = xs;
  __syncthreads();

  // y[e] = xhat_sum[e]*g[e] + K*b[e]  (folds LN affine + K-sum of bias)
  __shared__ float y[CMV];
  y[tid] = (xsum[0][tid] + xsum[1][tid] + xsum[2][tid] + xsum[3][tid]) * g[tid]
           + (float)KV * b[tid];
  __syncthreads();

  // projection: thread t handles c = t&31, e-chunk = t>>5 (8 chunks of 32)
  const int c     = tid & 31;
  const int chunk = tid >> 5;
  float p = 0.f;
  #pragma unroll
  for (int q = 0; q < 32; ++q) {
    const int e = (chunk << 5) + q;
    p = fmaf(y[e], Wag[(e << 5) + c], p);
  }
  __shared__ float pr[256];
  pr[tid] = p;
  __syncthreads();
  if (tid < 32) {
    float acc = 0.f;
    #pragma unroll
    for (int r = 0; r < 8; ++r) acc += pr[tid + (r << 5)];
    msum[(j << 5) + tid] = acc + (float)KV * bag[tid];
  }
}

// ---------------------------------------------------------------------------
// Kernel B1: a[i,c] = (LN(s[i,:])*g + b) @ W_ab + b_ab
// grid = 256 (block per row i), block = 384 (one thread per element)
// ---------------------------------------------------------------------------
__global__ __launch_bounds__(384) void a_kernel(
    const float* __restrict__ s, const float* __restrict__ g,
    const float* __restrict__ b, const float* __restrict__ Wab,
    const float* __restrict__ bab, float* __restrict__ a)
{
  const int i    = blockIdx.x;
  const int tid  = threadIdx.x;
  const int wave = tid >> 6;   // 0..5
  const int lane = tid & 63;

  const float x = s[i * CSV + tid];
  float s1 = x, s2 = x * x;
  #pragma unroll
  for (int off = 32; off > 0; off >>= 1) {
    s1 += __shfl_xor(s1, off, 64);
    s2 += __shfl_xor(s2, off, 64);
  }
  __shared__ float r1[6], r2[6];
  if (lane == 0) { r1[wave] = s1; r2[wave] = s2; }
  __syncthreads();
  float t1 = 0.f, t2 = 0.f;
  #pragma unroll
  for (int w = 0; w < 6; ++w) { t1 += r1[w]; t2 += r2[w]; }
  const float mu   = t1 * (1.0f / CSV);
  const float rstd = rsqrtf(t2 * (1.0f / CSV) - mu * mu + 1e-5f);

  __shared__ float y[CSV];
  y[tid] = (x - mu) * rstd * g[tid] + b[tid];
  __syncthreads();

  const int c     = tid & 31;
  const int chunk = tid >> 5;  // 0..11
  float p = 0.f;
  #pragma unroll
  for (int q = 0; q < 32; ++q) {
    const int e = (chunk << 5) + q;
    p = fmaf(y[e], Wab[(e << 5) + c], p);
  }
  __shared__ float pr[CSV];
  pr[tid] = p;
  __syncthreads();
  if (tid < 32) {
    float acc = 0.f;
    #pragma unroll
    for (int r = 0; r < 12; ++r) acc += pr[tid + (r << 5)];
    a[(i << 5) + tid] = acc + bab[tid];
  }
}

// ---------------------------------------------------------------------------
// Kernel B2: T[i,idx] = sum_c a[i,c] * W_out[c*4096 + idx], idx = e*128+z
// Rewritten R1: old version was L2-latency-bound (VALUBusy 2.3%, 91 us).
// Now: grid = (16 idx-chunks, 8 i-chunks), block = 256. a-tile (4 KB) in LDS
// (broadcast reads), W_out column values held in 32 VGPRs, 32 outputs/thread.
// ---------------------------------------------------------------------------
__global__ __launch_bounds__(256) void t_kernel(
    const float* __restrict__ a, const float* __restrict__ Wout,
    float* __restrict__ T)
{
  const int tid = threadIdx.x;
  const int idx = (blockIdx.x << 8) + tid;   // 0..4095
  const int i0  = blockIdx.y << 5;           // 0,32,...,224

  __shared__ float as[32 * 32];
  #pragma unroll
  for (int r = 0; r < 4; ++r) {
    const int t = (r << 8) + tid;
    as[t] = a[(i0 << 5) + t];
  }
  __syncthreads();

  float w[32];
  #pragma unroll
  for (int c = 0; c < 32; ++c) w[c] = Wout[(c << 12) + idx];

  #pragma unroll 4
  for (int ii = 0; ii < 32; ++ii) {
    float acc = 0.f;
    #pragma unroll
    for (int c = 0; c < 32; ++c)
      acc = fmaf(as[(ii << 5) + c], w[c], acc);
    T[((size_t)(i0 + ii) << 12) + idx] = acc;
  }
}

// ---------------------------------------------------------------------------
// Kernel C: out[i,j,z] = (m_sum[j,:] @ T[i][:,z] + b_out[z]) / (K + 1e-3)
// grid = (16 j-tiles, 256 i), block = 512 (R1: was 256; 8 waves/block for
// better store/LDS latency hiding). Thread owns a z-quad (T columns in 128
// VGPRs), loops 4 j's; m_sum tile (8 KB) in LDS, b128 broadcast reads.
// ---------------------------------------------------------------------------
__global__ __launch_bounds__(512) void out_kernel(
    const float* __restrict__ msum, const float* __restrict__ T,
    const float* __restrict__ bout, float* __restrict__ out)
{
  const int tile = blockIdx.x;   // 0..15
  const int i    = blockIdx.y;   // 0..255
  const int tid  = threadIdx.x;
  const int j0   = tile << 6;

  __shared__ float ms[64 * CHV];  // 2048 floats = 8 KB
  ((float4*)ms)[tid] = ((const float4*)(msum + ((size_t)j0 << 5)))[tid];

  const int zq = (tid & 31) << 2;  // z quad start: 0,4,...,124
  const int jg = tid >> 5;         // 0..15

  float4 Treg[32];
  #pragma unroll
  for (int e = 0; e < 32; ++e)
    Treg[e] = *(const float4*)(T + ((size_t)i << 12) + (e << 7) + zq);

  __syncthreads();

  const float4 bz = *(const float4*)(bout + zq);
  const float inv_norm = 1.0f / ((float)KV + 1e-3f);

  #pragma unroll
  for (int jj = 0; jj < 4; ++jj) {
    const int j = jg + (jj << 4);            // 0..63
    const float4* mr = (const float4*)(ms + (j << 5));
    float4 acc = f4zero();
    #pragma unroll
    for (int eq = 0; eq < 8; ++eq) {
      const float4 m4 = mr[eq];
      const float4 t0 = Treg[(eq << 2) + 0];
      const float4 t1 = Treg[(eq << 2) + 1];
      const float4 t2 = Treg[(eq << 2) + 2];
      const float4 t3 = Treg[(eq << 2) + 3];
      acc.x = fmaf(m4.x, t0.x, fmaf(m4.y, t1.x, fmaf(m4.z, t2.x, fmaf(m4.w, t3.x, acc.x))));
      acc.y = fmaf(m4.x, t0.y, fmaf(m4.y, t1.y, fmaf(m4.z, t2.y, fmaf(m4.w, t3.y, acc.y))));
      acc.z = fmaf(m4.x, t0.z, fmaf(m4.y, t1.z, fmaf(m4.z, t2.z, fmaf(m4.w, t3.z, acc.z))));
      acc.w = fmaf(m4.x, t0.w, fmaf(m4.y, t1.w, fmaf(m4.z, t2.w, fmaf(m4.w, t3.w, acc.w))));
    }
    float4 o;
    o.x = (acc.x + bz.x) * inv_norm;
    o.y = (acc.y + bz.y) * inv_norm;
    o.z = (acc.z + bz.z) * inv_norm;
    o.w = (acc.w + bz.w) * inv_norm;
    *(float4*)(out + ((size_t)i << 17) + ((size_t)(j0 + j) << 7) + zq) = o;
  }
}

// ---------------------------------------------------------------------------
extern "C" void kernel_launch(void* const* d_in, const int* in_sizes, int n_in,
                              void* d_out, int out_size, void* d_ws, size_t ws_size,
                              hipStream_t stream) {
  (void)in_sizes; (void)n_in; (void)out_size; (void)ws_size;
  const float* s    = (const float*)d_in[0];
  const float* m    = (const float*)d_in[1];
  const float* g_ab = (const float*)d_in[2];
  const float* b_ab = (const float*)d_in[3];
  const float* g_ag = (const float*)d_in[4];
  const float* b_ag = (const float*)d_in[5];
  const float* Wab  = (const float*)d_in[6];
  const float* bab  = (const float*)d_in[7];
  const float* Wag  = (const float*)d_in[8];
  const float* bag  = (const float*)d_in[9];
  const float* Wout = (const float*)d_in[10];
  const float* bout = (const float*)d_in[11];
  float* out = (float*)d_out;

  // workspace layout (fp32): msum[1024*32] | a[256*32] | T[256*32*128]
  float* msum = (float*)d_ws;
  float* a    = msum + 32768;
  float* T    = a + 8192;   // 4 MB

  hipLaunchKernelGGL(msum_kernel, dim3(1024), dim3(256), 0, stream,
                     m, g_ag, b_ag, Wag, bag, msum);
  hipLaunchKernelGGL(a_kernel, dim3(256), dim3(384), 0, stream,
                     s, g_ab, b_ab, Wab, bab, a);
  hipLaunchKernelGGL(t_kernel, dim3(16, 8), dim3(256), 0, stream,
                     a, Wout, T);
  hipLaunchKernelGGL(out_kernel, dim3(16, 256), dim3(512), 0, stream,
                     msum, T, bout, out);
}

// Round 3
// 280.204 us; speedup vs baseline: 1.2835x; 1.0688x over previous
//
#include <hip/hip_runtime.h>

// Shapes (fixed by setup_inputs): N=1, L1=256, K=128, L2=1024,
// c_s=384, c_m=256, ch=32, c_z=128
#define L1V 256
#define L2V 1024
#define KV  128
#define CSV 384
#define CMV 256
#define CHV 32
#define CZV 128

__device__ __forceinline__ float4 f4zero() { return make_float4(0.f,0.f,0.f,0.f); }

// Per-row LN stats (full-wave reduction over 256 elems = 64 lanes x float4),
// then accumulate normalized row into xs.
__device__ __forceinline__ void ln_accum(const float4 x, float4& xs) {
  float s1 = x.x + x.y + x.z + x.w;
  float s2 = fmaf(x.x, x.x, fmaf(x.y, x.y, fmaf(x.z, x.z, x.w * x.w)));
  #pragma unroll
  for (int off = 32; off > 0; off >>= 1) {
    s1 += __shfl_xor(s1, off, 64);
    s2 += __shfl_xor(s2, off, 64);
  }
  const float mu   = s1 * (1.0f / CMV);
  const float rstd = rsqrtf(s2 * (1.0f / CMV) - mu * mu + 1e-5f);
  xs.x = fmaf(x.x - mu, rstd, xs.x);
  xs.y = fmaf(x.y - mu, rstd, xs.y);
  xs.z = fmaf(x.z - mu, rstd, xs.z);
  xs.w = fmaf(x.w - mu, rstd, xs.w);
}

// ---------------------------------------------------------------------------
// Kernel A: m_sum[j,c] = sum_k (LN(m[k,j,:]) * g + b) @ W_ag + K*b_ag
// K-sum commutes inside the projection -> accumulate xhat, project once per j.
// grid = 1024 (block per j), block = 256; ~134 MB streamed, HBM-floor ~21 us.
// ---------------------------------------------------------------------------
__global__ __launch_bounds__(256) void msum_kernel(
    const float* __restrict__ m, const float* __restrict__ g,
    const float* __restrict__ b, const float* __restrict__ Wag,
    const float* __restrict__ bag, float* __restrict__ msum)
{
  const int j    = blockIdx.x;
  const int tid  = threadIdx.x;
  const int wave = tid >> 6;
  const int lane = tid & 63;

  const float4* base = (const float4*)m;  // row k at float4 index (k*1024+j)*64

  float4 xs = f4zero();
  float4 x0 = base[(((size_t)wave << 10) + j) * 64 + lane];
  float4 x1 = base[(((size_t)(wave + 4) << 10) + j) * 64 + lane];

  for (int k = wave; k < KV; k += 8) {
    float4 n0 = f4zero(), n1 = f4zero();
    if (k + 8  < KV) n0 = base[(((size_t)(k + 8)  << 10) + j) * 64 + lane];
    if (k + 12 < KV) n1 = base[(((size_t)(k + 12) << 10) + j) * 64 + lane];
    ln_accum(x0, xs);
    ln_accum(x1, xs);
    x0 = n0; x1 = n1;
  }

  __shared__ float xsum[4][CMV];
  ((float4*)xsum[wave])[lane] = xs;
  __syncthreads();

  // y[e] = xhat_sum[e]*g[e] + K*b[e]  (folds LN affine + K-sum of bias)
  __shared__ float y[CMV];
  y[tid] = (xsum[0][tid] + xsum[1][tid] + xsum[2][tid] + xsum[3][tid]) * g[tid]
           + (float)KV * b[tid];
  __syncthreads();

  // projection: thread t handles c = t&31, e-chunk = t>>5 (8 chunks of 32)
  const int c     = tid & 31;
  const int chunk = tid >> 5;
  float p = 0.f;
  #pragma unroll
  for (int q = 0; q < 32; ++q) {
    const int e = (chunk << 5) + q;
    p = fmaf(y[e], Wag[(e << 5) + c], p);
  }
  __shared__ float pr[256];
  pr[tid] = p;
  __syncthreads();
  if (tid < 32) {
    float acc = 0.f;
    #pragma unroll
    for (int r = 0; r < 8; ++r) acc += pr[tid + (r << 5)];
    msum[(j << 5) + tid] = acc + (float)KV * bag[tid];
  }
}

// ---------------------------------------------------------------------------
// Kernel B1: a[i,c] = (LN(s[i,:])*g + b) @ W_ab + b_ab
// grid = 256 (block per row i), block = 384 (one thread per element)
// ---------------------------------------------------------------------------
__global__ __launch_bounds__(384) void a_kernel(
    const float* __restrict__ s, const float* __restrict__ g,
    const float* __restrict__ b, const float* __restrict__ Wab,
    const float* __restrict__ bab, float* __restrict__ a)
{
  const int i    = blockIdx.x;
  const int tid  = threadIdx.x;
  const int wave = tid >> 6;   // 0..5
  const int lane = tid & 63;

  const float x = s[i * CSV + tid];
  float s1 = x, s2 = x * x;
  #pragma unroll
  for (int off = 32; off > 0; off >>= 1) {
    s1 += __shfl_xor(s1, off, 64);
    s2 += __shfl_xor(s2, off, 64);
  }
  __shared__ float r1[6], r2[6];
  if (lane == 0) { r1[wave] = s1; r2[wave] = s2; }
  __syncthreads();
  float t1 = 0.f, t2 = 0.f;
  #pragma unroll
  for (int w = 0; w < 6; ++w) { t1 += r1[w]; t2 += r2[w]; }
  const float mu   = t1 * (1.0f / CSV);
  const float rstd = rsqrtf(t2 * (1.0f / CSV) - mu * mu + 1e-5f);

  __shared__ float y[CSV];
  y[tid] = (x - mu) * rstd * g[tid] + b[tid];
  __syncthreads();

  const int c     = tid & 31;
  const int chunk = tid >> 5;  // 0..11
  float p = 0.f;
  #pragma unroll
  for (int q = 0; q < 32; ++q) {
    const int e = (chunk << 5) + q;
    p = fmaf(y[e], Wab[(e << 5) + c], p);
  }
  __shared__ float pr[CSV];
  pr[tid] = p;
  __syncthreads();
  if (tid < 32) {
    float acc = 0.f;
    #pragma unroll
    for (int r = 0; r < 12; ++r) acc += pr[tid + (r << 5)];
    a[(i << 5) + tid] = acc + bab[tid];
  }
}

// ---------------------------------------------------------------------------
// Kernel B2: T[i,idx] = sum_c a[i,c] * W_out[c*4096 + idx], idx = e*128+z
// grid = (16 idx-chunks, 16 i-chunks) = 256 blocks (R2: was 128, half the
// CUs idle). a-tile in LDS (broadcast), W_out column in 32 VGPRs.
// ---------------------------------------------------------------------------
__global__ __launch_bounds__(256) void t_kernel(
    const float* __restrict__ a, const float* __restrict__ Wout,
    float* __restrict__ T)
{
  const int tid = threadIdx.x;
  const int idx = (blockIdx.x << 8) + tid;   // 0..4095
  const int i0  = blockIdx.y << 4;           // 0,16,...,240

  __shared__ float as[16 * 32];
  #pragma unroll
  for (int r = 0; r < 2; ++r) {
    const int t = (r << 8) + tid;
    as[t] = a[(i0 << 5) + t];
  }
  __syncthreads();

  float w[32];
  #pragma unroll
  for (int c = 0; c < 32; ++c) w[c] = Wout[(c << 12) + idx];

  #pragma unroll 4
  for (int ii = 0; ii < 16; ++ii) {
    float acc = 0.f;
    #pragma unroll
    for (int c = 0; c < 32; ++c)
      acc = fmaf(as[(ii << 5) + c], w[c], acc);
    T[((size_t)(i0 + ii) << 12) + idx] = acc;
  }
}

// ---------------------------------------------------------------------------
// Kernel C: out[i,j,z] = (m_sum[j,:] @ T[i][:,z] + b_out[z]) / (K + 1e-3)
// R2 REWRITE: old grid (16,256) re-read each T row 16x -> ~1 GB of cross-XCD
// L2/L3 traffic (the hidden ~100+ us). Now grid = (2 j-halves, 256 i) = 512
// blocks (2/CU); T_i loaded ONCE into 128 VGPRs (8 MB total T traffic);
// msum staged through an 8 KB LDS tile, 8 tiles per block.
// Pipes: stores ~21 us (TA) | LDS broadcast ~20 us (DS) | FMA ~14 us (VALU)
// -> overlapped, store-bound.
// ---------------------------------------------------------------------------
__global__ __launch_bounds__(256) void out_kernel(
    const float* __restrict__ msum, const float* __restrict__ T,
    const float* __restrict__ bout, float* __restrict__ out)
{
  const int half = blockIdx.x;   // 0..1
  const int i    = blockIdx.y;   // 0..255
  const int tid  = threadIdx.x;
  const int zq   = (tid & 31) << 2;  // z quad start: 0,4,...,124
  const int jg   = tid >> 5;         // 0..7

  float4 Treg[32];
  #pragma unroll
  for (int e = 0; e < 32; ++e)
    Treg[e] = *(const float4*)(T + ((size_t)i << 12) + (e << 7) + zq);

  const float4 bz = *(const float4*)(bout + zq);
  const float inv_norm = 1.0f / ((float)KV + 1e-3f);

  __shared__ float ms[64 * CHV];  // 8 KB

  for (int tile = 0; tile < 8; ++tile) {
    const int j0 = (half << 9) + (tile << 6);
    __syncthreads();  // previous tile's reads done before overwrite
    ((float4*)ms)[tid]       = ((const float4*)(msum + ((size_t)j0 << 5)))[tid];
    ((float4*)ms)[tid + 256] = ((const float4*)(msum + ((size_t)j0 << 5)))[tid + 256];
    __syncthreads();

    #pragma unroll
    for (int jj = 0; jj < 8; ++jj) {
      const int j = jg + (jj << 3);            // 0..63 within tile
      const float4* mr = (const float4*)(ms + (j << 5));
      float4 acc = f4zero();
      #pragma unroll
      for (int eq = 0; eq < 8; ++eq) {
        const float4 m4 = mr[eq];
        const float4 t0 = Treg[(eq << 2) + 0];
        const float4 t1 = Treg[(eq << 2) + 1];
        const float4 t2 = Treg[(eq << 2) + 2];
        const float4 t3 = Treg[(eq << 2) + 3];
        acc.x = fmaf(m4.x, t0.x, fmaf(m4.y, t1.x, fmaf(m4.z, t2.x, fmaf(m4.w, t3.x, acc.x))));
        acc.y = fmaf(m4.x, t0.y, fmaf(m4.y, t1.y, fmaf(m4.z, t2.y, fmaf(m4.w, t3.y, acc.y))));
        acc.z = fmaf(m4.x, t0.z, fmaf(m4.y, t1.z, fmaf(m4.z, t2.z, fmaf(m4.w, t3.z, acc.z))));
        acc.w = fmaf(m4.x, t0.w, fmaf(m4.y, t1.w, fmaf(m4.z, t2.w, fmaf(m4.w, t3.w, acc.w))));
      }
      float4 o;
      o.x = (acc.x + bz.x) * inv_norm;
      o.y = (acc.y + bz.y) * inv_norm;
      o.z = (acc.z + bz.z) * inv_norm;
      o.w = (acc.w + bz.w) * inv_norm;
      *(float4*)(out + ((size_t)i << 17) + ((size_t)(j0 + j) << 7) + zq) = o;
    }
  }
}

// ---------------------------------------------------------------------------
extern "C" void kernel_launch(void* const* d_in, const int* in_sizes, int n_in,
                              void* d_out, int out_size, void* d_ws, size_t ws_size,
                              hipStream_t stream) {
  (void)in_sizes; (void)n_in; (void)out_size; (void)ws_size;
  const float* s    = (const float*)d_in[0];
  const float* m    = (const float*)d_in[1];
  const float* g_ab = (const float*)d_in[2];
  const float* b_ab = (const float*)d_in[3];
  const float* g_ag = (const float*)d_in[4];
  const float* b_ag = (const float*)d_in[5];
  const float* Wab  = (const float*)d_in[6];
  const float* bab  = (const float*)d_in[7];
  const float* Wag  = (const float*)d_in[8];
  const float* bag  = (const float*)d_in[9];
  const float* Wout = (const float*)d_in[10];
  const float* bout = (const float*)d_in[11];
  float* out = (float*)d_out;

  // workspace layout (fp32): msum[1024*32] | a[256*32] | T[256*32*128]
  float* msum = (float*)d_ws;
  float* a    = msum + 32768;
  float* T    = a + 8192;   // 4 MB

  hipLaunchKernelGGL(msum_kernel, dim3(1024), dim3(256), 0, stream,
                     m, g_ag, b_ag, Wag, bag, msum);
  hipLaunchKernelGGL(a_kernel, dim3(256), dim3(384), 0, stream,
                     s, g_ab, b_ab, Wab, bab, a);
  hipLaunchKernelGGL(t_kernel, dim3(16, 16), dim3(256), 0, stream,
                     a, Wout, T);
  hipLaunchKernelGGL(out_kernel, dim3(2, 256), dim3(256), 0, stream,
                     msum, T, bout, out);
}